// Round 3
// baseline (179.012 us; speedup 1.0000x reference)
//
#include <hip/hip_runtime.h>

typedef unsigned short u16;
typedef __attribute__((ext_vector_type(8))) short short8;
typedef __attribute__((ext_vector_type(4))) float float4v;

#define D_DIM 128
#define M_DIM 128
#define BQ 4096
#define BK 8192

// round-to-nearest-even fp32 -> bf16
static __device__ inline u16 f2bf(float f) {
    unsigned int x = __float_as_uint(f);
    unsigned int r = (x + 0x7FFFu + ((x >> 16) & 1u)) >> 16;
    return (u16)r;
}

// ---------------------------------------------------------------------------
// Projection: X (rows x 128) @ S^T in fp32 (round-1 proven numerics).
// 16 rows/block, 256 threads: thread t -> col m = t&127, group g = t>>7
// handles 8 rows via wave-uniform LDS broadcasts; S rows read per-thread.
// SIGNS=true : emit bf16 +-1 and normscale[row] = ||x|| * sqrt(pi/2)/128
// SIGNS=false: emit bf16 round of the projection (query path)
// ---------------------------------------------------------------------------
template <bool SIGNS>
__global__ __launch_bounds__(256) void proj_kernel(
    const float* __restrict__ X, const float* __restrict__ S,
    u16* __restrict__ out, float* __restrict__ normscale)
{
    __shared__ float rows[16 * 128];  // 8 KB
    const int tid = threadIdx.x;
    const int blk = blockIdx.x;

    const float4v* xs = (const float4v*)(X + (size_t)blk * 16 * 128);
    float4v* ls = (float4v*)rows;
    ls[tid]       = xs[tid];
    ls[tid + 256] = xs[tid + 256];
    __syncthreads();

    const int m = tid & 127;
    const int g = tid >> 7;

    float acc[8] = {0.f, 0.f, 0.f, 0.f, 0.f, 0.f, 0.f, 0.f};
    const float4v* S4 = (const float4v*)S;

    #pragma unroll 4
    for (int k4 = 0; k4 < 32; ++k4) {
        float4v s = S4[m * 32 + k4];
        #pragma unroll
        for (int rr = 0; rr < 8; ++rr) {
            float4v x = *(const float4v*)&rows[(g * 8 + rr) * 128 + k4 * 4];
            acc[rr] += s.x * x.x;
            acc[rr] += s.y * x.y;
            acc[rr] += s.z * x.z;
            acc[rr] += s.w * x.w;
        }
    }

    #pragma unroll
    for (int rr = 0; rr < 8; ++rr) {
        int row = blk * 16 + g * 8 + rr;
        u16 v;
        if (SIGNS) {
            v = (acc[rr] >= 0.f) ? (u16)0x3F80u : (u16)0xBF80u;
        } else {
            v = f2bf(acc[rr]);
        }
        out[(size_t)row * 128 + m] = v;
    }

    if (SIGNS) {
        const int r16 = tid >> 4;
        const int seg = tid & 15;
        float p = 0.f;
        #pragma unroll
        for (int e = 0; e < 8; ++e) {
            float v = rows[r16 * 128 + seg * 8 + e];
            p += v * v;
        }
        p += __shfl_xor(p, 1);
        p += __shfl_xor(p, 2);
        p += __shfl_xor(p, 4);
        p += __shfl_xor(p, 8);
        if (seg == 0) {
            const float scale = 1.2533141373155003f / 128.0f;  // sqrt(pi/2)/m
            normscale[blk * 16 + r16] = sqrtf(p) * scale;
        }
    }
}

// ---------------------------------------------------------------------------
// Main GEMM, NO-LDS version: out[i][j] = ns[j] * sum_k qp[i][k] * sg[j][k]
// K=128 and both operands are k-contiguous, so each wave loads its MFMA
// fragments DIRECTLY from global (L2-resident, 3 MB total): no LDS, no
// __syncthreads, no barrier drain. 128x128 tile per block, 4 waves 2x2,
// each wave 64x64 via 4x4 frags of mfma_f32_16x16x32_bf16, operands
// swapped (mfma(b,a)) so lanes hold 4 consecutive j -> float4 stores.
// ---------------------------------------------------------------------------
__global__ __launch_bounds__(256) void qjl_gemm(
    const u16* __restrict__ qp, const u16* __restrict__ sg,
    const float* __restrict__ ns, float* __restrict__ out)
{
    const int tid = threadIdx.x;
    const int lane = tid & 63;
    const int wid = tid >> 6;
    const int q = lane >> 4;            // quad 0..3
    const int r16 = lane & 15;
    const int j0 = blockIdx.x * 128;    // key tile
    const int i0 = blockIdx.y * 128;    // query tile
    const int wrow = (wid & 1) * 64;    // query offset of this wave
    const int wcol = (wid >> 1) * 64;   // key offset of this wave

    // fragment base pointers: row (i0+wrow+t*16+r16), k-chunk (kk*32+q*8)
    const u16* Abase = qp + (size_t)(i0 + wrow + r16) * 128 + q * 8;
    const u16* Bbase = sg + (size_t)(j0 + wcol + r16) * 128 + q * 8;

    // acc[jt][it]: D "row" (q*4+rg) = key j local, D "col" (r16) = query i
    float4v acc[4][4] = {};

    #pragma unroll
    for (int kk = 0; kk < 4; ++kk) {    // K steps of 32
        short8 a[4], b[4];
        #pragma unroll
        for (int t = 0; t < 4; ++t) {
            a[t] = *(const short8*)(Abase + t * 16 * 128 + kk * 32);
            b[t] = *(const short8*)(Bbase + t * 16 * 128 + kk * 32);
        }
        #pragma unroll
        for (int jt = 0; jt < 4; ++jt)
            #pragma unroll
            for (int it = 0; it < 4; ++it)
                acc[jt][it] = __builtin_amdgcn_mfma_f32_16x16x32_bf16(
                    b[jt], a[it], acc[jt][it], 0, 0, 0);
    }

    // epilogue: lane (q,r16): i = i0+wrow+it*16+r16, j = j0+wcol+jt*16+q*4+rg
    #pragma unroll
    for (int it = 0; it < 4; ++it) {
        const int i = i0 + wrow + it * 16 + r16;
        float* orow = out + (size_t)i * BK;
        #pragma unroll
        for (int jt = 0; jt < 4; ++jt) {
            const int jbase = j0 + wcol + jt * 16 + q * 4;
            const float4v ns4 = *(const float4v*)&ns[jbase];
            float4v v = acc[jt][it];
            v.x *= ns4.x; v.y *= ns4.y; v.z *= ns4.z; v.w *= ns4.w;
            *(float4v*)&orow[jbase] = v;
        }
    }
}

extern "C" void kernel_launch(void* const* d_in, const int* in_sizes, int n_in,
                              void* d_out, int out_size, void* d_ws, size_t ws_size,
                              hipStream_t stream) {
    const float* query    = (const float*)d_in[0];  // (4096, 128)
    const float* residual = (const float*)d_in[1];  // (8192, 128)
    const float* S        = (const float*)d_in[2];  // (128, 128)
    float* out = (float*)d_out;                     // (4096, 8192)

    char* ws = (char*)d_ws;
    u16*   qp = (u16*)ws;                       // 1 MB
    u16*   sg = (u16*)(ws + (1u << 20));        // 2 MB
    float* ns = (float*)(ws + (3u << 20));      // 32 KB

    proj_kernel<false><<<dim3(BQ / 16), 256, 0, stream>>>(query, S, qp, nullptr);
    proj_kernel<true><<<dim3(BK / 16), 256, 0, stream>>>(residual, S, sg, ns);
    qjl_gemm<<<dim3(BK / 128, BQ / 128), 256, 0, stream>>>(qp, sg, ns, out);
}

// Round 4
// 157.940 us; speedup vs baseline: 1.1334x; 1.1334x over previous
//
#include <hip/hip_runtime.h>

typedef unsigned short u16;
typedef __attribute__((ext_vector_type(8))) short short8;
typedef __attribute__((ext_vector_type(4))) float float4v;

#define D_DIM 128
#define M_DIM 128
#define BQ 4096
#define BK 8192

// round-to-nearest-even fp32 -> bf16
static __device__ inline u16 f2bf(float f) {
    unsigned int x = __float_as_uint(f);
    unsigned int r = (x + 0x7FFFu + ((x >> 16) & 1u)) >> 16;
    return (u16)r;
}

// ---------------------------------------------------------------------------
// Merged projection kernel: blocks [0,256) do query @ S^T -> bf16 qp;
// blocks [256,768) do residual @ S^T -> bf16 signs + normscale.
// 16 rows/block, 256 threads: thread t -> col m = t&127, group g = t>>7
// handles 8 rows via wave-uniform LDS broadcasts; S rows read per-thread
// (L1-resident, 64 KB). fp32 math matches numpy signs exactly enough
// (absmax 0.5 measured, threshold 2.11).
// ---------------------------------------------------------------------------
__global__ __launch_bounds__(256) void proj_both(
    const float* __restrict__ query, const float* __restrict__ residual,
    const float* __restrict__ S,
    u16* __restrict__ qp, u16* __restrict__ sg, float* __restrict__ normscale)
{
    __shared__ float rows[16 * 128];  // 8 KB
    const int tid = threadIdx.x;
    const bool is_res = blockIdx.x >= (BQ / 16);
    const int blk = is_res ? (blockIdx.x - BQ / 16) : blockIdx.x;
    const float* X = is_res ? residual : query;
    u16* out = is_res ? sg : qp;

    // stage 16 rows (2048 floats) contiguously, coalesced
    const float4v* xs = (const float4v*)(X + (size_t)blk * 16 * 128);
    float4v* ls = (float4v*)rows;
    ls[tid]       = xs[tid];
    ls[tid + 256] = xs[tid + 256];
    __syncthreads();

    const int m = tid & 127;
    const int g = tid >> 7;           // wave-uniform

    float acc[8] = {0.f, 0.f, 0.f, 0.f, 0.f, 0.f, 0.f, 0.f};
    const float4v* S4 = (const float4v*)S;

    #pragma unroll 4
    for (int k4 = 0; k4 < 32; ++k4) {
        float4v s = S4[m * 32 + k4];
        #pragma unroll
        for (int rr = 0; rr < 8; ++rr) {
            float4v x = *(const float4v*)&rows[(g * 8 + rr) * 128 + k4 * 4];
            acc[rr] += s.x * x.x;
            acc[rr] += s.y * x.y;
            acc[rr] += s.z * x.z;
            acc[rr] += s.w * x.w;
        }
    }

    if (is_res) {
        #pragma unroll
        for (int rr = 0; rr < 8; ++rr) {
            int row = blk * 16 + g * 8 + rr;
            out[(size_t)row * 128 + m] =
                (acc[rr] >= 0.f) ? (u16)0x3F80u : (u16)0xBF80u;
        }
        // norms: 16 threads per row, each sums 8 squares from LDS
        const int r16 = tid >> 4;
        const int seg = tid & 15;
        float p = 0.f;
        #pragma unroll
        for (int e = 0; e < 8; ++e) {
            float v = rows[r16 * 128 + seg * 8 + e];
            p += v * v;
        }
        p += __shfl_xor(p, 1);
        p += __shfl_xor(p, 2);
        p += __shfl_xor(p, 4);
        p += __shfl_xor(p, 8);
        if (seg == 0) {
            const float scale = 1.2533141373155003f / 128.0f;  // sqrt(pi/2)/m
            normscale[blk * 16 + r16] = sqrtf(p) * scale;
        }
    } else {
        #pragma unroll
        for (int rr = 0; rr < 8; ++rr) {
            int row = blk * 16 + g * 8 + rr;
            out[(size_t)row * 128 + m] = f2bf(acc[rr]);
        }
    }
}

// ---------------------------------------------------------------------------
// Main GEMM (round-2 proven best): out[i][j] = ns[j] * sum_k qp[i][k]*sg[j][k]
// 128x128 tile/block, 4 waves 2x2, each wave 64x64 via 4x4 frags of
// mfma_f32_16x16x32_bf16, operands swapped (mfma(b,a)) so each lane's 4 acc
// regs are 4 consecutive j in one query row -> float4 stores. K=128 staged
// once into LDS (stride 136 u16 -> 2-way bank aliasing only, free).
// Sits at the HBM-write roofline (~134 MB out): ~21-25 us.
// ---------------------------------------------------------------------------
__global__ __launch_bounds__(256) void qjl_gemm(
    const u16* __restrict__ qp, const u16* __restrict__ sg,
    const float* __restrict__ ns, float* __restrict__ out)
{
    __shared__ u16 Asm[128 * 136];
    __shared__ u16 Bsm[128 * 136];

    const int tid = threadIdx.x;
    const int j0 = blockIdx.x * 128;  // key tile
    const int i0 = blockIdx.y * 128;  // query tile

    const uint4* As = (const uint4*)(qp + (size_t)i0 * 128);
    const uint4* Bs = (const uint4*)(sg + (size_t)j0 * 128);
    #pragma unroll
    for (int i = 0; i < 8; ++i) {
        int c = tid + i * 256;          // 16B chunk id, 2048 per tile
        int row = c >> 4;
        int col8 = (c & 15) << 3;
        *(uint4*)&Asm[row * 136 + col8] = As[c];
        *(uint4*)&Bsm[row * 136 + col8] = Bs[c];
    }
    __syncthreads();

    const int lane = tid & 63;
    const int wid = tid >> 6;
    const int q = lane >> 4;            // quad 0..3
    const int r16 = lane & 15;
    const int wrow = (wid & 1) * 64;    // query offset of this wave
    const int wcol = (wid >> 1) * 64;   // key offset of this wave

    float4v acc[4][4] = {};

    #pragma unroll
    for (int kk = 0; kk < 4; ++kk) {    // K steps of 32
        short8 a[4], b[4];
        #pragma unroll
        for (int t = 0; t < 4; ++t) {
            a[t] = *(const short8*)&Asm[(wrow + t * 16 + r16) * 136 + kk * 32 + q * 8];
            b[t] = *(const short8*)&Bsm[(wcol + t * 16 + r16) * 136 + kk * 32 + q * 8];
        }
        #pragma unroll
        for (int jt = 0; jt < 4; ++jt)
            #pragma unroll
            for (int it = 0; it < 4; ++it)
                acc[jt][it] = __builtin_amdgcn_mfma_f32_16x16x32_bf16(
                    b[jt], a[it], acc[jt][it], 0, 0, 0);
    }

    // epilogue: lane (q,r16): i = i0+wrow+it*16+r16, j = j0+wcol+jt*16+q*4+rg
    #pragma unroll
    for (int it = 0; it < 4; ++it) {
        const int i = i0 + wrow + it * 16 + r16;
        float* orow = out + (size_t)i * BK;
        #pragma unroll
        for (int jt = 0; jt < 4; ++jt) {
            const int jbase = j0 + wcol + jt * 16 + q * 4;
            const float4v ns4 = *(const float4v*)&ns[jbase];
            float4v v = acc[jt][it];
            v.x *= ns4.x; v.y *= ns4.y; v.z *= ns4.z; v.w *= ns4.w;
            *(float4v*)&orow[jbase] = v;
        }
    }
}

extern "C" void kernel_launch(void* const* d_in, const int* in_sizes, int n_in,
                              void* d_out, int out_size, void* d_ws, size_t ws_size,
                              hipStream_t stream) {
    const float* query    = (const float*)d_in[0];  // (4096, 128)
    const float* residual = (const float*)d_in[1];  // (8192, 128)
    const float* S        = (const float*)d_in[2];  // (128, 128)
    float* out = (float*)d_out;                     // (4096, 8192)

    char* ws = (char*)d_ws;
    u16*   qp = (u16*)ws;                       // 1 MB
    u16*   sg = (u16*)(ws + (1u << 20));        // 2 MB
    float* ns = (float*)(ws + (3u << 20));      // 32 KB

    // one launch for both projections (blocks 0..255 query, 256..767 residual)
    proj_both<<<dim3(BQ / 16 + BK / 16), 256, 0, stream>>>(
        query, residual, S, qp, sg, ns);
    // main GEMM + epilogue scale
    qjl_gemm<<<dim3(BK / 128, BQ / 128), 256, 0, stream>>>(qp, sg, ns, out);
}